// Round 4
// baseline (106.645 us; speedup 1.0000x reference)
//
#include <hip/hip_runtime.h>
#include <hip/hip_bf16.h>

#define NN 8192
#define DD 128

typedef short bf16x8 __attribute__((ext_vector_type(8)));
typedef float f32x4 __attribute__((ext_vector_type(4)));

// A and B are converted on the fly from fp32 F, scaled by CSCALE so the MFMA
// output d = CSCALE^2 * s = (10*log2e) * s and e^{10 s} = exp2f(d) directly.
// Shift-free softmax: |d| <= 14.43 -> exp2 in [2^-14.4, 2^14.4], row sums
// < 2e8, fine in f32. sum over pos logits = (lr ? Sl : S - Sl) * ln2 via
// in-loop accumulation of d (no class-sum buffer, no prep pass needed).
#define CSCALE  3.7982829f      /* sqrt(10*log2(e)) */
#define LN2     0.69314718056f

// ws layout: control scalars + per-row stats, all zeroed by one tiny memset
#define CTR_OFF  0               /* int ctr[32]: per-rowgroup col-block ctr */
#define CTRC_OFF 128             /* float ctrC[32]: label-1 col count */
#define CTR2_OFF 256             /* int: rowgroup-done counter */
#define ACC_OFF  260             /* float: loss accumulator */
#define EG_OFF   512             /* 4 x NN floats follow */
#define ELG_OFF  (EG_OFF + NN * 4)
#define SG_OFF   (ELG_OFF + NN * 4)
#define SLG_OFF  (SG_OFF + NN * 4)
#define WS_ZERO  (SLG_OFF + NN * 4)   /* 131584 B */

// loss geometry: 512 blocks = 32 row-groups x 16 col-groups
// block = 4 waves x 64 rows/wave = 256 rows x 512 cols
#define BROWS 256
#define BCOLS 512
#define TCOLS 32                 /* cols per LDS tile */
#define ITERS (BCOLS / TCOLS)    /* 16 */

__device__ __forceinline__ bf16x8 cvt8(float4 fa, float4 fb) {
    union { __hip_bfloat16 h[8]; bf16x8 v; } u;
    u.h[0] = __float2bfloat16(CSCALE * fa.x);
    u.h[1] = __float2bfloat16(CSCALE * fa.y);
    u.h[2] = __float2bfloat16(CSCALE * fa.z);
    u.h[3] = __float2bfloat16(CSCALE * fa.w);
    u.h[4] = __float2bfloat16(CSCALE * fb.x);
    u.h[5] = __float2bfloat16(CSCALE * fb.y);
    u.h[6] = __float2bfloat16(CSCALE * fb.z);
    u.h[7] = __float2bfloat16(CSCALE * fb.w);
    return u.v;
}

// Single worker kernel (normal launch): 512 blocks x 256 threads, 2 blocks/CU.
// No prep pass: A-fragments and B-tiles are converted fp32->bf16 in-kernel
// (F is 4MB -> fully L2/L3 resident; redundant reads are cache hits, not HBM).
// Cross-block transport is the R2-proven pattern: per-row atomicAdd stats +
// per-rowgroup atomic counter gate; the 16th col-block of each rowgroup
// finalizes its 256 rows; the 32nd finalize block writes out.
__global__ __launch_bounds__(256, 2) void fused_kernel(
        const float* __restrict__ F, const int* __restrict__ labels,
        int* __restrict__ ctr, float* __restrict__ ctrC,
        int* __restrict__ ctr2, float* __restrict__ acc,
        float* __restrict__ Eg, float* __restrict__ Elg,
        float* __restrict__ Sg, float* __restrict__ Slg,
        float* __restrict__ out) {
    __shared__ unsigned short Bt[2][TCOLS * DD];   // 2 x 8KB
    __shared__ float Lab[BCOLS];
    __shared__ int sLast;
    __shared__ float wsum[4];
    const int tid  = threadIdx.x;
    const int bid  = blockIdx.x;
    const int wave = tid >> 6, lane = tid & 63;
    const int quad = lane >> 4, l16 = lane & 15;
    const int rg = bid & 31;
    const int rb = rg * BROWS;
    const int cb = (bid >> 5) * BCOLS;

    Lab[tid]       = (float)labels[cb + tid];
    Lab[tid + 256] = (float)labels[cb + tid + 256];

    // A fragments: wave owns rows rw..rw+63 (4 m-tiles); fp32 load + convert.
    const int rw = rb + wave * 64;
    bf16x8 a[4][4];
    #pragma unroll
    for (int m = 0; m < 4; m++)
        #pragma unroll
        for (int kb = 0; kb < 4; kb++) {
            const float* ap = F + (rw + m * 16 + l16) * DD + kb * 32 + quad * 8;
            const float4 fa = *reinterpret_cast<const float4*>(ap);
            const float4 fb = *reinterpret_cast<const float4*>(ap + 4);
            a[m][kb] = cvt8(fa, fb);
        }

    // cooperative staging map: thread -> col = tid>>3, 16 consecutive floats
    const int scol = tid >> 3;           // 0..31
    const int sc0  = (tid & 7) * 2;      // k-chunk pair (each 8 elems)
    const float* sbaseF = F + (cb + scol) * DD + sc0 * 8;
    const int sdst0 = sc0 * (TCOLS * 8) + (((scol ^ sc0) & 31) * 8);
    const int sdst1 = (sc0 + 1) * (TCOLS * 8) + (((scol ^ (sc0 + 1)) & 31) * 8);

    // stage tile 0 (load fp32, convert, swizzled LDS store)
    {
        const float4 va = *reinterpret_cast<const float4*>(sbaseF + 0);
        const float4 vb = *reinterpret_cast<const float4*>(sbaseF + 4);
        const float4 vc = *reinterpret_cast<const float4*>(sbaseF + 8);
        const float4 vd = *reinterpret_cast<const float4*>(sbaseF + 12);
        *reinterpret_cast<bf16x8*>(&Bt[0][sdst0]) = cvt8(va, vb);
        *reinterpret_cast<bf16x8*>(&Bt[0][sdst1]) = cvt8(vc, vd);
    }

    float accE[4][4] = {}, accEl[4][4] = {};
    float accS[4][4] = {}, accSl[4][4] = {};
    __syncthreads();

    // per-rowgroup label-1 column count: each wave sums a distinct 128-col
    // slice; 4 waves x 16 col-blocks cover all 8192 cols exactly once.
    {
        float cc = Lab[wave * 64 + lane] + Lab[256 + wave * 64 + lane];
        #pragma unroll
        for (int off = 1; off < 64; off <<= 1) cc += __shfl_xor(cc, off);
        if (lane == 0) atomicAdd(&ctrC[rg], cc);
    }

    for (int it = 0; it < ITERS; ++it) {
        const int cur = it & 1;
        const int itn = (it + 1) & (ITERS - 1);   // wrap: last prefetch harmless
        const float* pf = sbaseF + itn * TCOLS * DD;
        const float4 va = *reinterpret_cast<const float4*>(pf + 0);
        const float4 vb = *reinterpret_cast<const float4*>(pf + 4);
        const float4 vc = *reinterpret_cast<const float4*>(pf + 8);
        const float4 vd = *reinterpret_cast<const float4*>(pf + 12);

        #pragma unroll
        for (int g = 0; g < 2; ++g) {
            bf16x8 bfr[4];
            #pragma unroll
            for (int kb = 0; kb < 4; kb++) {
                const int cr = kb * 4 + quad;
                const int col = g * 16 + l16;
                bfr[kb] = *reinterpret_cast<const bf16x8*>(
                    &Bt[cur][cr * (TCOLS * 8) + (((col ^ cr) & 31) * 8)]);
            }
            f32x4 d0 = {0.f, 0.f, 0.f, 0.f}, d1 = {0.f, 0.f, 0.f, 0.f};
            f32x4 d2 = {0.f, 0.f, 0.f, 0.f}, d3 = {0.f, 0.f, 0.f, 0.f};
            #pragma unroll
            for (int kb = 0; kb < 4; kb++) {
                d0 = __builtin_amdgcn_mfma_f32_16x16x32_bf16(a[0][kb], bfr[kb], d0, 0, 0, 0);
                d1 = __builtin_amdgcn_mfma_f32_16x16x32_bf16(a[1][kb], bfr[kb], d1, 0, 0, 0);
                d2 = __builtin_amdgcn_mfma_f32_16x16x32_bf16(a[2][kb], bfr[kb], d2, 0, 0, 0);
                d3 = __builtin_amdgcn_mfma_f32_16x16x32_bf16(a[3][kb], bfr[kb], d3, 0, 0, 0);
            }
            const float lc = Lab[it * TCOLS + g * 16 + l16];
            #pragma unroll
            for (int r = 0; r < 4; r++) {
                const float e0 = exp2f(d0[r]);
                accE[0][r] += e0; accEl[0][r] = fmaf(lc, e0, accEl[0][r]);
                accS[0][r] += d0[r]; accSl[0][r] = fmaf(lc, d0[r], accSl[0][r]);
                const float e1 = exp2f(d1[r]);
                accE[1][r] += e1; accEl[1][r] = fmaf(lc, e1, accEl[1][r]);
                accS[1][r] += d1[r]; accSl[1][r] = fmaf(lc, d1[r], accSl[1][r]);
                const float e2 = exp2f(d2[r]);
                accE[2][r] += e2; accEl[2][r] = fmaf(lc, e2, accEl[2][r]);
                accS[2][r] += d2[r]; accSl[2][r] = fmaf(lc, d2[r], accSl[2][r]);
                const float e3 = exp2f(d3[r]);
                accE[3][r] += e3; accEl[3][r] = fmaf(lc, e3, accEl[3][r]);
                accS[3][r] += d3[r]; accSl[3][r] = fmaf(lc, d3[r], accSl[3][r]);
            }
        }

        *reinterpret_cast<bf16x8*>(&Bt[cur ^ 1][sdst0]) = cvt8(va, vb);
        *reinterpret_cast<bf16x8*>(&Bt[cur ^ 1][sdst1]) = cvt8(vc, vd);
        __syncthreads();
    }

    // 16-lane row reduce, then one global atomic per (row, stat)
    #pragma unroll
    for (int m = 0; m < 4; m++) {
        #pragma unroll
        for (int r = 0; r < 4; r++) {
            float e = accE[m][r], el = accEl[m][r];
            float s = accS[m][r], sl = accSl[m][r];
            #pragma unroll
            for (int off = 1; off < 16; off <<= 1) {
                e  += __shfl_xor(e,  off);
                el += __shfl_xor(el, off);
                s  += __shfl_xor(s,  off);
                sl += __shfl_xor(sl, off);
            }
            if (l16 == 0) {
                const int row = rw + m * 16 + quad * 4 + r;
                atomicAdd(&Eg[row], e);
                atomicAdd(&Elg[row], el);
                atomicAdd(&Sg[row], s);
                atomicAdd(&Slg[row], sl);
            }
        }
    }

    // ---- fused finalize (R2-proven gate): last col-block of the rowgroup ----
    __syncthreads();   // drains vmcnt: all this block's atomics are complete
    if (tid == 0) sLast = (atomicAdd(&ctr[rg], 1) == 15);
    __syncthreads();
    if (!sLast) return;

    const int row = rb + tid;
    const int lr  = labels[row];
    const float E   = atomicAdd(&Eg[row], 0.f);    // coherent atomic-loads
    const float El  = atomicAdd(&Elg[row], 0.f);
    const float S   = atomicAdd(&Sg[row], 0.f);
    const float Sl  = atomicAdd(&Slg[row], 0.f);
    const float c1f = atomicAdd(&ctrC[rg], 0.f);   // each block's ctrC add
                                                   // preceded its ctr add
    const float Epos = lr ? El : (E - El);         // pos exp-sum (incl diag)
    const float Si   = E - Epos;                   // neg exp-sum
    const float cntp1 = lr ? c1f : ((float)NN - c1f);
    const float cntm  = cntp1 - 1.f;
    const float sum_l   = (lr ? Sl : (S - Sl)) * LN2;  // sum over pos logits
    const float sum_log = cntp1 * __logf(Si) + Epos / Si;
    float li = -(10.f / 7.f) * (sum_l - sum_log) / cntm;
    #pragma unroll
    for (int off = 1; off < 64; off <<= 1) li += __shfl_xor(li, off);
    if ((tid & 63) == 0) wsum[tid >> 6] = li;
    __syncthreads();
    if (tid == 0) {
        atomicAdd(acc, (wsum[0] + wsum[1] + wsum[2] + wsum[3]) * (1.0f / NN));
        __threadfence();   // order acc-add before ctr2-add (32 blocks only)
        if (atomicAdd(ctr2, 1) == 31) out[0] = atomicAdd(acc, 0.f);
    }
}

extern "C" void kernel_launch(void* const* d_in, const int* in_sizes, int n_in,
                              void* d_out, int out_size, void* d_ws, size_t ws_size,
                              hipStream_t stream) {
    const float* F      = (const float*)d_in[0];
    const int*   labels = (const int*)d_in[1];
    float*       out    = (float*)d_out;
    char*        ws     = (char*)d_ws;
    int*         ctr    = (int*)(ws + CTR_OFF);
    float*       ctrC   = (float*)(ws + CTRC_OFF);
    int*         ctr2   = (int*)(ws + CTR2_OFF);
    float*       acc    = (float*)(ws + ACC_OFF);
    float*       Eg     = (float*)(ws + EG_OFF);
    float*       Elg    = (float*)(ws + ELG_OFF);
    float*       Sg     = (float*)(ws + SG_OFF);
    float*       Slg    = (float*)(ws + SLG_OFF);

    // one tiny memset: control scalars + 4 per-row stat arrays (128.5 KB)
    hipMemsetAsync(ws, 0, WS_ZERO, stream);

    fused_kernel<<<512, 256, 0, stream>>>(F, labels, ctr, ctrC, ctr2, acc,
                                          Eg, Elg, Sg, Slg, out);
}